// Round 11
// baseline (514.798 us; speedup 1.0000x reference)
//
#include <hip/hip_runtime.h>
#include <hip/hip_bf16.h>
#include <math.h>
#include <stdint.h>

#define D_MODEL 768
#define D_INNER 1536
#define D_STATE 16
#define DT_RANK 48
#define NB 2
#define LL 1024
#define MROWS (NB*LL)     // 2048
#define NXZ (2*D_INNER)   // 3072
#define NDBC 80

typedef __attribute__((ext_vector_type(8))) short short8;
typedef __attribute__((ext_vector_type(4))) float f32x4;

__device__ __forceinline__ float silu_f(float x) {
  return x / (1.0f + __expf(-x));
}
__device__ __forceinline__ float softplus_f(float x) {
  return (x >= 20.0f) ? x : log1pf(__expf(x));
}

// fp32 -> bf16 round-to-nearest-even (finite inputs)
__device__ __forceinline__ ushort f2bf(float x) {
  union { float f; uint32_t u; } v; v.f = x;
  return (ushort)((v.u + 0x7FFFu + ((v.u >> 16) & 1u)) >> 16);
}
__device__ __forceinline__ float bf2f(ushort h) {
  union { uint32_t u; float f; } v; v.u = ((uint32_t)h) << 16;
  return v.f;
}

__device__ __forceinline__ void g2l16(const void* g, void* l) {
  __builtin_amdgcn_global_load_lds(
      (const __attribute__((address_space(1))) uint32_t*)g,
      (__attribute__((address_space(3))) uint32_t*)l, 16, 0, 0);
}

// LDS k-slot swizzle mask: uniform 2-way bank distribution (free per m136)
__device__ __forceinline__ int swz(int row) {
  return (row ^ (row >> 2)) & 3;
}

// ---------------------------------------------------------------------------
// split convert: hi = bf16(x), lo = bf16(x - hi)
// ---------------------------------------------------------------------------
__global__ __launch_bounds__(256)
void cvt_split_kernel(const float* __restrict__ in, ushort* __restrict__ hi,
                      ushort* __restrict__ lo, int n4) {
  int i = blockIdx.x * 256 + threadIdx.x;
  if (i >= n4) return;
  float4 v = *(const float4*)&in[i*4];
  ushort4 h, l;
  h.x = f2bf(v.x); l.x = f2bf(v.x - bf2f(h.x));
  h.y = f2bf(v.y); l.y = f2bf(v.y - bf2f(h.y));
  h.z = f2bf(v.z); l.z = f2bf(v.z - bf2f(h.z));
  h.w = f2bf(v.w); l.w = f2bf(v.w - bf2f(h.w));
  *(ushort4*)&hi[i*4] = h;
  *(ushort4*)&lo[i*4] = l;
}

// ---------------------------------------------------------------------------
// bf16 MFMA GEMM (NT): C[m,n] = sum_k A[m,k]*W[n,k], A/W given as hi/lo bf16.
// 3-term compensation: Ah*Bh + Ah*Bl + Al*Bh  (fp32-class accuracy).
// ---------------------------------------------------------------------------
template<int BM, int BN>
__global__ __launch_bounds__(256)
void gemm_mfma(const ushort* __restrict__ Ah, const ushort* __restrict__ Al,
               const ushort* __restrict__ Bh, const ushort* __restrict__ Bl,
               float* __restrict__ C, int M, int N, int K) {
  constexpr int MR = BM / 32;   // 16-row frags per wave (m)
  constexpr int NR = BN / 32;   // 16-col frags per wave (n)
  __shared__ __align__(16) ushort sAh[BM*32];
  __shared__ __align__(16) ushort sAl[BM*32];
  __shared__ __align__(16) ushort sBh[BN*32];
  __shared__ __align__(16) ushort sBl[BN*32];

  const int tid  = threadIdx.x;
  const int w    = tid >> 6;
  const int lane = tid & 63;
  const int wr   = w >> 1, wc = w & 1;
  const int bm   = blockIdx.x * BM, bn = blockIdx.y * BN;

  const int rA = lane >> 2;      // staging: row within 16-row group
  const int ps = lane & 3;       // staging: physical 16B slot
  const int kg = lane >> 4;      // frag: k-group (0..3)
  const int fr = lane & 15;      // frag: row/col within 16

  f32x4 acc[MR][NR];
  #pragma unroll
  for (int mi = 0; mi < MR; ++mi)
    #pragma unroll
    for (int ni = 0; ni < NR; ++ni) acc[mi][ni] = (f32x4){0.f,0.f,0.f,0.f};

  for (int k0 = 0; k0 < K; k0 += 32) {
    __syncthreads();   // previous tile fully consumed
    #pragma unroll
    for (int q = 0; q < BM/64; ++q) {
      int row = q*64 + w*16 + rA;
      int kch = ps ^ swz(row);                  // swizzled source chunk
      size_t go = (size_t)(bm + row)*K + k0 + kch*8;
      g2l16(Ah + go, (ushort*)sAh + (q*64 + w*16)*32);  // wave-uniform base
      g2l16(Al + go, (ushort*)sAl + (q*64 + w*16)*32);
    }
    #pragma unroll
    for (int q = 0; q < BN/64; ++q) {
      int row = q*64 + w*16 + rA;
      int kch = ps ^ swz(row);
      size_t go = (size_t)(bn + row)*K + k0 + kch*8;
      g2l16(Bh + go, (ushort*)sBh + (q*64 + w*16)*32);
      g2l16(Bl + go, (ushort*)sBl + (q*64 + w*16)*32);
    }
    __syncthreads();   // compiler drains vmcnt(0) before s_barrier -> staged data visible

    short8 ah[MR], al[MR], bh[NR], bl[NR];
    #pragma unroll
    for (int mi = 0; mi < MR; ++mi) {
      int row  = wr*(BM/2) + mi*16 + fr;
      int slot = kg ^ swz(row);
      ah[mi] = *(const short8*)((const char*)sAh + row*64 + slot*16);
      al[mi] = *(const short8*)((const char*)sAl + row*64 + slot*16);
    }
    #pragma unroll
    for (int ni = 0; ni < NR; ++ni) {
      int row  = wc*(BN/2) + ni*16 + fr;
      int slot = kg ^ swz(row);
      bh[ni] = *(const short8*)((const char*)sBh + row*64 + slot*16);
      bl[ni] = *(const short8*)((const char*)sBl + row*64 + slot*16);
    }
    #pragma unroll
    for (int mi = 0; mi < MR; ++mi)
      #pragma unroll
      for (int ni = 0; ni < NR; ++ni) {
        acc[mi][ni] = __builtin_amdgcn_mfma_f32_16x16x32_bf16(ah[mi], bh[ni], acc[mi][ni], 0, 0, 0);
        acc[mi][ni] = __builtin_amdgcn_mfma_f32_16x16x32_bf16(ah[mi], bl[ni], acc[mi][ni], 0, 0, 0);
        acc[mi][ni] = __builtin_amdgcn_mfma_f32_16x16x32_bf16(al[mi], bh[ni], acc[mi][ni], 0, 0, 0);
      }
  }

  // epilogue: D row = kg*4 + r, col = fr  (m89-verified C/D mapping)
  #pragma unroll
  for (int mi = 0; mi < MR; ++mi)
    #pragma unroll
    for (int ni = 0; ni < NR; ++ni) {
      #pragma unroll
      for (int r = 0; r < 4; ++r) {
        int m = bm + wr*(BM/2) + mi*16 + kg*4 + r;
        int n = bn + wc*(BN/2) + ni*16 + fr;
        C[(size_t)m*N + n] = acc[mi][ni][r];
      }
    }
}

// ---------------------------------------------------------------------------
// Causal depthwise conv (D_CONV=4) + bias + SiLU.
// ---------------------------------------------------------------------------
__global__ __launch_bounds__(256)
void conv_silu_kernel(const float* __restrict__ xz, const float* __restrict__ cw,
                      const float* __restrict__ cb, float* __restrict__ xsc) {
  int idx = blockIdx.x * 256 + threadIdx.x;
  if (idx >= MROWS * D_INNER) return;
  int e   = idx % D_INNER;
  int row = idx / D_INNER;
  int l   = row % LL;
  const float* base = xz + (size_t)row * NXZ + e;
  float s = cb[e];
  #pragma unroll
  for (int j = 0; j < 4; ++j) {
    int dl = j - 3;
    if (l + dl >= 0) {
      int off = dl * NXZ;
      s = fmaf(cw[e*4 + j], base[off], s);
    }
  }
  xsc[idx] = silu_f(s);
}

// ---------------------------------------------------------------------------
// Tiled transpose: xsc[m][e] (2048x1536) -> xsc_t[e][m] (1536x2048).
// ---------------------------------------------------------------------------
__global__ __launch_bounds__(256)
void transpose_kernel(const float* __restrict__ in, float* __restrict__ outT) {
  __shared__ float T[64][65];
  const int m0 = blockIdx.x * 64;
  const int e0 = blockIdx.y * 64;
  const int cr = threadIdx.x >> 4;        // 0..15
  const int cc = (threadIdx.x & 15) * 4;  // 0..60
  for (int rr = cr; rr < 64; rr += 16) {
    float4 v = *(const float4*)&in[(size_t)(m0 + rr)*D_INNER + e0 + cc];
    T[rr][cc+0] = v.x; T[rr][cc+1] = v.y; T[rr][cc+2] = v.z; T[rr][cc+3] = v.w;
  }
  __syncthreads();
  for (int er = cr; er < 64; er += 16) {
    float4 v = make_float4(T[cc+0][er], T[cc+1][er], T[cc+2][er], T[cc+3][er]);
    *(float4*)&outT[(size_t)(e0 + er)*MROWS + m0 + cc] = v;
  }
}

__global__ __launch_bounds__(256)
void zero_kernel(float* __restrict__ p, int n) {
  int i = blockIdx.x * 256 + threadIdx.x;
  if (i < n) p[i] = 0.0f;
}

// ---------------------------------------------------------------------------
// x_proj for BOTH directions, split-K with atomicAdd epilogue.
// ---------------------------------------------------------------------------
#define XP_BM 16
#define XP_KC 192
__global__ __launch_bounds__(256)
void xproj_kernel(const float* __restrict__ xsc, const float* __restrict__ wf,
                  const float* __restrict__ wb, float* __restrict__ dbcf,
                  float* __restrict__ dbcb) {
  __shared__ __align__(16) float As[16][XP_BM];
  __shared__ __align__(16) float Ws[16][164];
  const int m0    = blockIdx.x * XP_BM;
  const int kbase = blockIdx.y * XP_KC;
  const int tid = threadIdx.x;
  const int tx = tid & 31;
  const int ty = tid >> 5;
  float acc[2][5] = {};
  for (int k0 = kbase; k0 < kbase + XP_KC; k0 += 16) {
    __syncthreads();
    if (tid < 64) {
      int r = tid >> 2, c = (tid & 3) * 4;
      float4 v = *(const float4*)&xsc[(size_t)(m0 + r)*D_INNER + k0 + c];
      As[c+0][r] = v.x; As[c+1][r] = v.y; As[c+2][r] = v.z; As[c+3][r] = v.w;
    }
    for (int q = tid; q < 640; q += 256) {
      int r = q >> 2, c = (q & 3) * 4;
      const float* src = (r < 80) ? &wf[(size_t)r*D_INNER + k0 + c]
                                  : &wb[(size_t)(r-80)*D_INNER + k0 + c];
      float4 v = *(const float4*)src;
      Ws[c+0][r] = v.x; Ws[c+1][r] = v.y; Ws[c+2][r] = v.z; Ws[c+3][r] = v.w;
    }
    __syncthreads();
    #pragma unroll
    for (int kk = 0; kk < 16; ++kk) {
      float a0 = As[kk][ty*2 + 0];
      float a1 = As[kk][ty*2 + 1];
      #pragma unroll
      for (int j = 0; j < 5; ++j) {
        float w = Ws[kk][tx*5 + j];
        acc[0][j] = fmaf(a0, w, acc[0][j]);
        acc[1][j] = fmaf(a1, w, acc[1][j]);
      }
    }
  }
  #pragma unroll
  for (int i = 0; i < 2; ++i) {
    int m = m0 + ty*2 + i;
    #pragma unroll
    for (int j = 0; j < 5; ++j) {
      int n = tx*5 + j;
      float v = acc[i][j];
      if (n < 80) atomicAdd(&dbcf[(size_t)m*NDBC + n], v);
      else        atomicAdd(&dbcb[(size_t)m*NDBC + (n-80)], v);
    }
  }
}

// ---------------------------------------------------------------------------
// delta_t = softplus(dbc[:, :48] @ dtw^T + dtb) TRANSPOSED to [e][m] layout
// ---------------------------------------------------------------------------
__global__ __launch_bounds__(256)
void delta_kernel(const float* __restrict__ dbcf, const float* __restrict__ dbcb,
                  const float* __restrict__ dtwf, const float* __restrict__ dtwb,
                  const float* __restrict__ dtbf, const float* __restrict__ dtbb,
                  float* __restrict__ outf, float* __restrict__ outb) {
  const int dir = blockIdx.z;
  const float* dbc = dir ? dbcb : dbcf;
  const float* dtw = dir ? dtwb : dtwf;
  const float* dtb = dir ? dtbb : dtbf;
  float* out = dir ? outb : outf;            // [e][m] layout (1536 x 2048)
  __shared__ __align__(16) float As[48][36];
  __shared__ __align__(16) float Ws[48][132];
  __shared__ float T[128][33];
  const int m0 = blockIdx.x * 32;
  const int e0 = blockIdx.y * 128;
  const int tid = threadIdx.x;
  const int tx = tid & 31;
  const int ty = tid >> 5;
  for (int q = tid; q < 384; q += 256) {
    int r = q / 12, c = (q % 12) * 4;
    float4 v = *(const float4*)&dbc[(size_t)(m0 + r)*NDBC + c];
    As[c+0][r] = v.x; As[c+1][r] = v.y; As[c+2][r] = v.z; As[c+3][r] = v.w;
  }
  for (int q = tid; q < 1536; q += 256) {
    int r = q / 12, c = (q % 12) * 4;
    float4 v = *(const float4*)&dtw[(size_t)(e0 + r)*DT_RANK + c];
    Ws[c+0][r] = v.x; Ws[c+1][r] = v.y; Ws[c+2][r] = v.z; Ws[c+3][r] = v.w;
  }
  __syncthreads();
  float acc[4][4] = {};
  #pragma unroll
  for (int kk = 0; kk < 48; ++kk) {
    float4 a = *(const float4*)&As[kk][ty*4];
    float4 w = *(const float4*)&Ws[kk][tx*4];
    float av[4] = {a.x, a.y, a.z, a.w};
    float wv[4] = {w.x, w.y, w.z, w.w};
    #pragma unroll
    for (int i = 0; i < 4; ++i)
      #pragma unroll
      for (int j = 0; j < 4; ++j)
        acc[i][j] = fmaf(av[i], wv[j], acc[i][j]);
  }
  // softplus + stage transposed: T[e_local][m_local]
  #pragma unroll
  for (int i = 0; i < 4; ++i)
    #pragma unroll
    for (int j = 0; j < 4; ++j)
      T[tx*4 + j][ty*4 + i] = softplus_f(acc[i][j] + dtb[e0 + tx*4 + j]);
  __syncthreads();
  // write out [e][m]: thread -> (row r=tid>>1 of 128, half h=tid&1 of 32m)
  {
    int r = tid >> 1, h = (tid & 1) * 16;
    float* dst = out + (size_t)(e0 + r)*MROWS + m0 + h;
    #pragma unroll
    for (int q = 0; q < 4; ++q) {
      float4 v = make_float4(T[r][h+q*4+0], T[r][h+q*4+1], T[r][h+q*4+2], T[r][h+q*4+3]);
      *(float4*)(dst + q*4) = v;
    }
  }
}

// ---------------------------------------------------------------------------
// Chunked two-pass selective scan, [e][m] operands, QUAD-STATE lanes:
// wave = 16 e-channels x 4 lanes; each lane owns 4 states (n-quad) in regs.
// B/C loads are broadcast float4s; shfl chain is 2 (not 4); y-writes are
// 64B-coalesced. Block = 16 waves = 16 chunks of one (dir,b,16e) group.
// ---------------------------------------------------------------------------
#define SC_C 16
#define SC_P 64
__global__ __launch_bounds__(1024)
void scan_kernel(const float* __restrict__ dltf, const float* __restrict__ dltb,
                 const float* __restrict__ dbcf, const float* __restrict__ dbcb,
                 const float* __restrict__ xst,
                 const float* __restrict__ Alogf, const float* __restrict__ Alogb,
                 float* __restrict__ yf, float* __restrict__ yb) {
  __shared__ float sA[SC_C][16][16];
  __shared__ float sH[SC_C][16][16];
  __shared__ float sI[SC_C][16][16];
  const int blk = blockIdx.x;              // [0, 384)
  const int dir = blk / 192;
  const int b   = (blk % 192) / 96;
  const int e0  = (blk % 96) * 16;
  const int tid = threadIdx.x;
  const int c   = tid >> 6;                // chunk = wave id
  const int lane = tid & 63;
  const int el  = lane >> 2;               // e within group (0..15)
  const int q   = lane & 3;                // n-quad (0..3)
  const int e   = e0 + el;

  const float* dlt  = dir ? dltb  : dltf;
  const float* dbc  = dir ? dbcb  : dbcf;
  const float* Alog = dir ? Alogb : Alogf;
  float* y          = dir ? yb    : yf;

  const float LOG2E = 1.4426950408889634f;
  float4 av = *(const float4*)&Alog[e*D_STATE + q*4];
  float a2[4] = { -__expf(av.x)*LOG2E, -__expf(av.y)*LOG2E,
                  -__expf(av.z)*LOG2E, -__expf(av.w)*LOG2E };

  const int sg = dir ? -1 : 1;
  const int l0 = dir ? (LL - 1 - c*SC_P) : (c*SC_P);

  const float* dp0 = dlt + (size_t)e * MROWS + b * LL + l0;           // walk +/-1
  const float* xp0 = xst + (size_t)e * MROWS + b * LL + l0;
  const float* bp0 = dbc + ((size_t)b * LL + l0) * NDBC + DT_RANK + q*4;  // f4, +/-80
  const int bstep = sg * NDBC;

  // ---- pass 1: chunk-local (prod dA, h_loc), 4 states/lane
  float Ap[4] = {1.f,1.f,1.f,1.f}, hh[4] = {0.f,0.f,0.f,0.f};
  {
    const float* d = dp0; const float* x = xp0; const float* bc = bp0;
    #pragma unroll 4
    for (int i = 0; i < SC_P; ++i) {
      const float dl = *d, xv = *x;
      const float4 B = *(const float4*)bc;
      const float u = dl * xv;
      const float Bv[4] = {B.x, B.y, B.z, B.w};
      #pragma unroll
      for (int j = 0; j < 4; ++j) {
        const float dA = exp2f(dl * a2[j]);
        hh[j] = fmaf(dA, hh[j], u * Bv[j]);
        Ap[j] *= dA;
      }
      d += sg; x += sg; bc += bstep;
    }
  }
  #pragma unroll
  for (int j = 0; j < 4; ++j) {
    sA[c][el][q*4+j] = Ap[j];
    sH[c][el][q*4+j] = hh[j];
  }
  __syncthreads();

  // ---- combine: exclusive prefix over chunks; one thread per (e,n) state
  if (tid < 256) {
    const int ee = tid >> 4, nn = tid & 15;
    float carry = 0.0f;
    #pragma unroll
    for (int cc = 0; cc < SC_C; ++cc) {
      sI[cc][ee][nn] = carry;
      carry = fmaf(sA[cc][ee][nn], carry, sH[cc][ee][nn]);
    }
  }
  __syncthreads();

  // ---- pass 2: re-scan from corrected initial state, emit y
  float h[4];
  #pragma unroll
  for (int j = 0; j < 4; ++j) h[j] = sI[c][el][q*4+j];
  {
    const float* d = dp0; const float* x = xp0; const float* bc = bp0;
    float* yw = y + (size_t)b * LL * D_INNER + e + (size_t)l0 * D_INNER;  // +/-1536
    const int ystep = sg * (int)D_INNER;
    #pragma unroll 4
    for (int i = 0; i < SC_P; ++i) {
      const float dl = *d, xv = *x;
      const float4 B = *(const float4*)bc;
      const float4 C = *(const float4*)(bc + D_STATE);
      const float u = dl * xv;
      const float Bv[4] = {B.x, B.y, B.z, B.w};
      const float Cv[4] = {C.x, C.y, C.z, C.w};
      float p = 0.0f;
      #pragma unroll
      for (int j = 0; j < 4; ++j) {
        const float dA = exp2f(dl * a2[j]);
        h[j] = fmaf(dA, h[j], u * Bv[j]);
        p = fmaf(h[j], Cv[j], p);
      }
      p += __shfl_xor(p, 1);
      p += __shfl_xor(p, 2);
      if (q == 0) *yw = p;
      d += sg; x += sg; bc += bstep; yw += ystep;
    }
  }
}

// ---------------------------------------------------------------------------
// gate: g = (y_f + y_b + (D + D_b) * xs_c) * silu(z), emitted as hi/lo bf16
// ---------------------------------------------------------------------------
__global__ __launch_bounds__(256)
void gate_kernel(const float* __restrict__ yf, const float* __restrict__ yb,
                 const float* __restrict__ xsc, const float* __restrict__ xz,
                 const float* __restrict__ Dp, const float* __restrict__ Db,
                 ushort* __restrict__ ghi, ushort* __restrict__ glo) {
  int i4 = blockIdx.x * 256 + threadIdx.x;
  if (i4 >= MROWS * D_INNER / 4) return;
  int idx = i4 * 4;
  int e   = idx % D_INNER;
  int row = idx / D_INNER;
  float4 vf = *(const float4*)&yf[idx];
  float4 vb = *(const float4*)&yb[idx];
  float4 vx = *(const float4*)&xsc[idx];
  float4 vz = *(const float4*)&xz[(size_t)row*NXZ + D_INNER + e];
  float4 vD  = *(const float4*)&Dp[e];
  float4 vDb = *(const float4*)&Db[e];
  float4 o;
  o.x = fmaf(vD.x + vDb.x, vx.x, vf.x + vb.x) * silu_f(vz.x);
  o.y = fmaf(vD.y + vDb.y, vx.y, vf.y + vb.y) * silu_f(vz.y);
  o.z = fmaf(vD.z + vDb.z, vx.z, vf.z + vb.z) * silu_f(vz.z);
  o.w = fmaf(vD.w + vDb.w, vx.w, vf.w + vb.w) * silu_f(vz.w);
  ushort4 h, l;
  h.x = f2bf(o.x); l.x = f2bf(o.x - bf2f(h.x));
  h.y = f2bf(o.y); l.y = f2bf(o.y - bf2f(h.y));
  h.z = f2bf(o.z); l.z = f2bf(o.z - bf2f(h.z));
  h.w = f2bf(o.w); l.w = f2bf(o.w - bf2f(h.w));
  *(ushort4*)&ghi[idx] = h;
  *(ushort4*)&glo[idx] = l;
}

// ---------------------------------------------------------------------------
extern "C" void kernel_launch(void* const* d_in, const int* in_sizes, int n_in,
                              void* d_out, int out_size, void* d_ws, size_t ws_size,
                              hipStream_t stream) {
  const float* x     = (const float*)d_in[0];
  const float* ipw   = (const float*)d_in[1];
  const float* cw    = (const float*)d_in[2];
  const float* cb    = (const float*)d_in[3];
  const float* xpwf  = (const float*)d_in[4];
  const float* dtwf  = (const float*)d_in[5];
  const float* dtbf  = (const float*)d_in[6];
  const float* Alogf = (const float*)d_in[7];
  const float* Dpf   = (const float*)d_in[8];
  const float* opw   = (const float*)d_in[9];
  const float* Alogb = (const float*)d_in[10];
  const float* xpwb  = (const float*)d_in[11];
  const float* dtwb  = (const float*)d_in[12];
  const float* dtbb  = (const float*)d_in[13];
  const float* Dpb   = (const float*)d_in[14];
  float* out = (float*)d_out;

  float* ws = (float*)d_ws;
  float* xz   = ws;                                   // 2048*3072 f32
  float* xsc  = xz   + (size_t)MROWS * NXZ;           // 2048*1536 f32 [m][e]
  float* dbcf = xsc  + (size_t)MROWS * D_INNER;
  float* dbcb = dbcf + (size_t)MROWS * NDBC;
  float* dltf = dbcb + (size_t)MROWS * NDBC;          // [e][m]; reused: g hi/lo
  float* dltb = dltf + (size_t)MROWS * D_INNER;       // [e][m]
  float* yfb  = dltb + (size_t)MROWS * D_INNER;
  float* ybb  = yfb  + (size_t)MROWS * D_INNER;
  // bf16 aliases: x hi/lo in yfb region (dead until scan); ipw hi/lo in ybb.
  ushort* xhi   = (ushort*)yfb;
  ushort* xlo   = xhi   + (size_t)MROWS * D_MODEL;
  ushort* ipwhi = (ushort*)ybb;
  ushort* ipwlo = ipwhi + (size_t)NXZ * D_MODEL;
  // persistent regions after the f32 buffers:
  ushort* opwhi = (ushort*)(ybb + (size_t)MROWS * D_INNER);
  ushort* opwlo = opwhi + (size_t)D_MODEL * D_INNER;
  float*  xst   = (float*)(opwlo + (size_t)D_MODEL * D_INNER);  // xsc_t [e][m] 12.6MB
  // g hi/lo reuse the (dead-after-scan) dltf region
  ushort* ghi = (ushort*)dltf;
  ushort* glo = ghi + (size_t)MROWS * D_INNER;

  // 0) split-convert x, in_proj_w, out_proj_w to hi/lo bf16
  cvt_split_kernel<<<dim3(MROWS*D_MODEL/4/256), 256, 0, stream>>>(x, xhi, xlo, MROWS*D_MODEL/4);
  cvt_split_kernel<<<dim3(NXZ*D_MODEL/4/256), 256, 0, stream>>>(ipw, ipwhi, ipwlo, NXZ*D_MODEL/4);
  cvt_split_kernel<<<dim3(D_MODEL*D_INNER/4/256), 256, 0, stream>>>(opw, opwhi, opwlo, D_MODEL*D_INNER/4);

  // 1) xz = x @ in_proj_w^T  via MFMA (2048 x 3072, K=768)
  gemm_mfma<128,128><<<dim3(MROWS/128, NXZ/128), 256, 0, stream>>>(
      xhi, xlo, ipwhi, ipwlo, xz, MROWS, NXZ, D_MODEL);
  // 2) conv + bias + silu -> xsc [m][e]
  conv_silu_kernel<<<dim3((MROWS*D_INNER)/256), 256, 0, stream>>>(xz, cw, cb, xsc);
  // 2b) transpose xsc -> xst [e][m] for the scan
  transpose_kernel<<<dim3(MROWS/64, D_INNER/64), 256, 0, stream>>>(xsc, xst);
  // 3) zero dbc, then split-K x_proj (both dirs)
  zero_kernel<<<dim3((MROWS*2*NDBC + 255)/256), 256, 0, stream>>>(dbcf, MROWS*2*NDBC);
  xproj_kernel<<<dim3(MROWS/XP_BM, D_INNER/XP_KC), 256, 0, stream>>>(
      xsc, xpwf, xpwb, dbcf, dbcb);
  // 4) delta (both dirs) -> TRANSPOSED [e][m]
  delta_kernel<<<dim3(MROWS/32, D_INNER/128, 2), 256, 0, stream>>>(
      dbcf, dbcb, dtwf, dtwb, dtbf, dtbb, dltf, dltb);
  // 5) chunked two-pass scan, quad-state lanes (384 blocks x 1024 thr)
  scan_kernel<<<dim3(384), 1024, 0, stream>>>(
      dltf, dltb, dbcf, dbcb, xst, Alogf, Alogb, yfb, ybb);
  // 6) gate -> g hi/lo bf16 (dltf region dead after scan)
  gate_kernel<<<dim3((MROWS*D_INNER/4)/256), 256, 0, stream>>>(
      yfb, ybb, xsc, xz, Dpf, Dpb, ghi, glo);
  // 7) out = g @ out_proj_w^T via MFMA (2048 x 768, K=1536), 384 blocks
  gemm_mfma<64,64><<<dim3(MROWS/64, D_MODEL/64), 256, 0, stream>>>(
      ghi, glo, opwhi, opwlo, out, MROWS, D_MODEL, D_INNER);
}

// Round 14
// 468.512 us; speedup vs baseline: 1.0988x; 1.0988x over previous
//
#include <hip/hip_runtime.h>
#include <hip/hip_bf16.h>
#include <math.h>
#include <stdint.h>

#define D_MODEL 768
#define D_INNER 1536
#define D_STATE 16
#define DT_RANK 48
#define NB 2
#define LL 1024
#define MROWS (NB*LL)     // 2048
#define NXZ (2*D_INNER)   // 3072
#define NDBC 80

typedef __attribute__((ext_vector_type(8))) short short8;
typedef __attribute__((ext_vector_type(4))) float f32x4;

__device__ __forceinline__ float silu_f(float x) {
  return x / (1.0f + __expf(-x));
}
__device__ __forceinline__ float softplus_f(float x) {
  return (x >= 20.0f) ? x : log1pf(__expf(x));
}

// fp32 -> bf16 round-to-nearest-even (finite inputs)
__device__ __forceinline__ ushort f2bf(float x) {
  union { float f; uint32_t u; } v; v.f = x;
  return (ushort)((v.u + 0x7FFFu + ((v.u >> 16) & 1u)) >> 16);
}
__device__ __forceinline__ float bf2f(ushort h) {
  union { uint32_t u; float f; } v; v.u = ((uint32_t)h) << 16;
  return v.f;
}

__device__ __forceinline__ void g2l16(const void* g, void* l) {
  __builtin_amdgcn_global_load_lds(
      (const __attribute__((address_space(1))) uint32_t*)g,
      (__attribute__((address_space(3))) uint32_t*)l, 16, 0, 0);
}

// LDS k-slot swizzle mask: uniform 2-way bank distribution (free per m136)
__device__ __forceinline__ int swz(int row) {
  return (row ^ (row >> 2)) & 3;
}

// DPP row-shifted add: p += value from lane (i - N) within the 16-lane row;
// out-of-row lanes contribute 0 (bound_ctrl=1). After N=1,2,4,8 lane 15 of
// each row holds the full 16-lane sum. VALU-only (no LDS pipe).
// CTRL must be a compile-time constant (builtin requirement) -> template.
template<int CTRL>
__device__ __forceinline__ float dpp_shr_add(float p) {
  int t = __builtin_amdgcn_update_dpp(0, __float_as_int(p), CTRL, 0xf, 0xf, true);
  return p + __int_as_float(t);
}

// ---------------------------------------------------------------------------
// split convert: hi = bf16(x), lo = bf16(x - hi)
// ---------------------------------------------------------------------------
__global__ __launch_bounds__(256)
void cvt_split_kernel(const float* __restrict__ in, ushort* __restrict__ hi,
                      ushort* __restrict__ lo, int n4) {
  int i = blockIdx.x * 256 + threadIdx.x;
  if (i >= n4) return;
  float4 v = *(const float4*)&in[i*4];
  ushort4 h, l;
  h.x = f2bf(v.x); l.x = f2bf(v.x - bf2f(h.x));
  h.y = f2bf(v.y); l.y = f2bf(v.y - bf2f(h.y));
  h.z = f2bf(v.z); l.z = f2bf(v.z - bf2f(h.z));
  h.w = f2bf(v.w); l.w = f2bf(v.w - bf2f(h.w));
  *(ushort4*)&hi[i*4] = h;
  *(ushort4*)&lo[i*4] = l;
}

// ---------------------------------------------------------------------------
// bf16 MFMA GEMM (NT): C[m,n] = sum_k A[m,k]*W[n,k], A/W given as hi/lo bf16.
// 3-term compensation: Ah*Bh + Ah*Bl + Al*Bh  (fp32-class accuracy).
// ---------------------------------------------------------------------------
template<int BM, int BN>
__global__ __launch_bounds__(256)
void gemm_mfma(const ushort* __restrict__ Ah, const ushort* __restrict__ Al,
               const ushort* __restrict__ Bh, const ushort* __restrict__ Bl,
               float* __restrict__ C, int M, int N, int K) {
  constexpr int MR = BM / 32;   // 16-row frags per wave (m)
  constexpr int NR = BN / 32;   // 16-col frags per wave (n)
  __shared__ __align__(16) ushort sAh[BM*32];
  __shared__ __align__(16) ushort sAl[BM*32];
  __shared__ __align__(16) ushort sBh[BN*32];
  __shared__ __align__(16) ushort sBl[BN*32];

  const int tid  = threadIdx.x;
  const int w    = tid >> 6;
  const int lane = tid & 63;
  const int wr   = w >> 1, wc = w & 1;
  const int bm   = blockIdx.x * BM, bn = blockIdx.y * BN;

  const int rA = lane >> 2;      // staging: row within 16-row group
  const int ps = lane & 3;       // staging: physical 16B slot
  const int kg = lane >> 4;      // frag: k-group (0..3)
  const int fr = lane & 15;      // frag: row/col within 16

  f32x4 acc[MR][NR];
  #pragma unroll
  for (int mi = 0; mi < MR; ++mi)
    #pragma unroll
    for (int ni = 0; ni < NR; ++ni) acc[mi][ni] = (f32x4){0.f,0.f,0.f,0.f};

  for (int k0 = 0; k0 < K; k0 += 32) {
    __syncthreads();   // previous tile fully consumed
    #pragma unroll
    for (int q = 0; q < BM/64; ++q) {
      int row = q*64 + w*16 + rA;
      int kch = ps ^ swz(row);                  // swizzled source chunk
      size_t go = (size_t)(bm + row)*K + k0 + kch*8;
      g2l16(Ah + go, (ushort*)sAh + (q*64 + w*16)*32);  // wave-uniform base
      g2l16(Al + go, (ushort*)sAl + (q*64 + w*16)*32);
    }
    #pragma unroll
    for (int q = 0; q < BN/64; ++q) {
      int row = q*64 + w*16 + rA;
      int kch = ps ^ swz(row);
      size_t go = (size_t)(bn + row)*K + k0 + kch*8;
      g2l16(Bh + go, (ushort*)sBh + (q*64 + w*16)*32);
      g2l16(Bl + go, (ushort*)sBl + (q*64 + w*16)*32);
    }
    __syncthreads();   // compiler drains vmcnt(0) before s_barrier -> staged data visible

    short8 ah[MR], al[MR], bh[NR], bl[NR];
    #pragma unroll
    for (int mi = 0; mi < MR; ++mi) {
      int row  = wr*(BM/2) + mi*16 + fr;
      int slot = kg ^ swz(row);
      ah[mi] = *(const short8*)((const char*)sAh + row*64 + slot*16);
      al[mi] = *(const short8*)((const char*)sAl + row*64 + slot*16);
    }
    #pragma unroll
    for (int ni = 0; ni < NR; ++ni) {
      int row  = wc*(BN/2) + ni*16 + fr;
      int slot = kg ^ swz(row);
      bh[ni] = *(const short8*)((const char*)sBh + row*64 + slot*16);
      bl[ni] = *(const short8*)((const char*)sBl + row*64 + slot*16);
    }
    #pragma unroll
    for (int mi = 0; mi < MR; ++mi)
      #pragma unroll
      for (int ni = 0; ni < NR; ++ni) {
        acc[mi][ni] = __builtin_amdgcn_mfma_f32_16x16x32_bf16(ah[mi], bh[ni], acc[mi][ni], 0, 0, 0);
        acc[mi][ni] = __builtin_amdgcn_mfma_f32_16x16x32_bf16(ah[mi], bl[ni], acc[mi][ni], 0, 0, 0);
        acc[mi][ni] = __builtin_amdgcn_mfma_f32_16x16x32_bf16(al[mi], bh[ni], acc[mi][ni], 0, 0, 0);
      }
  }

  // epilogue: D row = kg*4 + r, col = fr  (m89-verified C/D mapping)
  #pragma unroll
  for (int mi = 0; mi < MR; ++mi)
    #pragma unroll
    for (int ni = 0; ni < NR; ++ni) {
      #pragma unroll
      for (int r = 0; r < 4; ++r) {
        int m = bm + wr*(BM/2) + mi*16 + kg*4 + r;
        int n = bn + wc*(BN/2) + ni*16 + fr;
        C[(size_t)m*N + n] = acc[mi][ni][r];
      }
    }
}

// ---------------------------------------------------------------------------
// Causal depthwise conv (D_CONV=4) + bias + SiLU.
// ---------------------------------------------------------------------------
__global__ __launch_bounds__(256)
void conv_silu_kernel(const float* __restrict__ xz, const float* __restrict__ cw,
                      const float* __restrict__ cb, float* __restrict__ xsc) {
  int idx = blockIdx.x * 256 + threadIdx.x;
  if (idx >= MROWS * D_INNER) return;
  int e   = idx % D_INNER;
  int row = idx / D_INNER;
  int l   = row % LL;
  const float* base = xz + (size_t)row * NXZ + e;
  float s = cb[e];
  #pragma unroll
  for (int j = 0; j < 4; ++j) {
    int dl = j - 3;
    if (l + dl >= 0) {
      int off = dl * NXZ;
      s = fmaf(cw[e*4 + j], base[off], s);
    }
  }
  xsc[idx] = silu_f(s);
}

// ---------------------------------------------------------------------------
// Tiled transpose: xsc[m][e] (2048x1536) -> xsc_t[e][m] (1536x2048).
// ---------------------------------------------------------------------------
__global__ __launch_bounds__(256)
void transpose_kernel(const float* __restrict__ in, float* __restrict__ outT) {
  __shared__ float T[64][65];
  const int m0 = blockIdx.x * 64;
  const int e0 = blockIdx.y * 64;
  const int cr = threadIdx.x >> 4;        // 0..15
  const int cc = (threadIdx.x & 15) * 4;  // 0..60
  for (int rr = cr; rr < 64; rr += 16) {
    float4 v = *(const float4*)&in[(size_t)(m0 + rr)*D_INNER + e0 + cc];
    T[rr][cc+0] = v.x; T[rr][cc+1] = v.y; T[rr][cc+2] = v.z; T[rr][cc+3] = v.w;
  }
  __syncthreads();
  for (int er = cr; er < 64; er += 16) {
    float4 v = make_float4(T[cc+0][er], T[cc+1][er], T[cc+2][er], T[cc+3][er]);
    *(float4*)&outT[(size_t)(e0 + er)*MROWS + m0 + cc] = v;
  }
}

__global__ __launch_bounds__(256)
void zero_kernel(float* __restrict__ p, int n) {
  int i = blockIdx.x * 256 + threadIdx.x;
  if (i < n) p[i] = 0.0f;
}

// ---------------------------------------------------------------------------
// x_proj for BOTH directions, split-K with atomicAdd epilogue.
// ---------------------------------------------------------------------------
#define XP_BM 16
#define XP_KC 192
__global__ __launch_bounds__(256)
void xproj_kernel(const float* __restrict__ xsc, const float* __restrict__ wf,
                  const float* __restrict__ wb, float* __restrict__ dbcf,
                  float* __restrict__ dbcb) {
  __shared__ __align__(16) float As[16][XP_BM];
  __shared__ __align__(16) float Ws[16][164];
  const int m0    = blockIdx.x * XP_BM;
  const int kbase = blockIdx.y * XP_KC;
  const int tid = threadIdx.x;
  const int tx = tid & 31;
  const int ty = tid >> 5;
  float acc[2][5] = {};
  for (int k0 = kbase; k0 < kbase + XP_KC; k0 += 16) {
    __syncthreads();
    if (tid < 64) {
      int r = tid >> 2, c = (tid & 3) * 4;
      float4 v = *(const float4*)&xsc[(size_t)(m0 + r)*D_INNER + k0 + c];
      As[c+0][r] = v.x; As[c+1][r] = v.y; As[c+2][r] = v.z; As[c+3][r] = v.w;
    }
    for (int q = tid; q < 640; q += 256) {
      int r = q >> 2, c = (q & 3) * 4;
      const float* src = (r < 80) ? &wf[(size_t)r*D_INNER + k0 + c]
                                  : &wb[(size_t)(r-80)*D_INNER + k0 + c];
      float4 v = *(const float4*)src;
      Ws[c+0][r] = v.x; Ws[c+1][r] = v.y; Ws[c+2][r] = v.z; Ws[c+3][r] = v.w;
    }
    __syncthreads();
    #pragma unroll
    for (int kk = 0; kk < 16; ++kk) {
      float a0 = As[kk][ty*2 + 0];
      float a1 = As[kk][ty*2 + 1];
      #pragma unroll
      for (int j = 0; j < 5; ++j) {
        float w = Ws[kk][tx*5 + j];
        acc[0][j] = fmaf(a0, w, acc[0][j]);
        acc[1][j] = fmaf(a1, w, acc[1][j]);
      }
    }
  }
  #pragma unroll
  for (int i = 0; i < 2; ++i) {
    int m = m0 + ty*2 + i;
    #pragma unroll
    for (int j = 0; j < 5; ++j) {
      int n = tx*5 + j;
      float v = acc[i][j];
      if (n < 80) atomicAdd(&dbcf[(size_t)m*NDBC + n], v);
      else        atomicAdd(&dbcb[(size_t)m*NDBC + (n-80)], v);
    }
  }
}

// ---------------------------------------------------------------------------
// delta_t = softplus(dbc[:, :48] @ dtw^T + dtb) TRANSPOSED to [e][m] layout
// ---------------------------------------------------------------------------
__global__ __launch_bounds__(256)
void delta_kernel(const float* __restrict__ dbcf, const float* __restrict__ dbcb,
                  const float* __restrict__ dtwf, const float* __restrict__ dtwb,
                  const float* __restrict__ dtbf, const float* __restrict__ dtbb,
                  float* __restrict__ outf, float* __restrict__ outb) {
  const int dir = blockIdx.z;
  const float* dbc = dir ? dbcb : dbcf;
  const float* dtw = dir ? dtwb : dtwf;
  const float* dtb = dir ? dtbb : dtbf;
  float* out = dir ? outb : outf;            // [e][m] layout (1536 x 2048)
  __shared__ __align__(16) float As[48][36];
  __shared__ __align__(16) float Ws[48][132];
  __shared__ float T[128][33];
  const int m0 = blockIdx.x * 32;
  const int e0 = blockIdx.y * 128;
  const int tid = threadIdx.x;
  const int tx = tid & 31;
  const int ty = tid >> 5;
  for (int q = tid; q < 384; q += 256) {
    int r = q / 12, c = (q % 12) * 4;
    float4 v = *(const float4*)&dbc[(size_t)(m0 + r)*NDBC + c];
    As[c+0][r] = v.x; As[c+1][r] = v.y; As[c+2][r] = v.z; As[c+3][r] = v.w;
  }
  for (int q = tid; q < 1536; q += 256) {
    int r = q / 12, c = (q % 12) * 4;
    float4 v = *(const float4*)&dtw[(size_t)(e0 + r)*DT_RANK + c];
    Ws[c+0][r] = v.x; Ws[c+1][r] = v.y; Ws[c+2][r] = v.z; Ws[c+3][r] = v.w;
  }
  __syncthreads();
  float acc[4][4] = {};
  #pragma unroll
  for (int kk = 0; kk < 48; ++kk) {
    float4 a = *(const float4*)&As[kk][ty*4];
    float4 w = *(const float4*)&Ws[kk][tx*4];
    float av[4] = {a.x, a.y, a.z, a.w};
    float wv[4] = {w.x, w.y, w.z, w.w};
    #pragma unroll
    for (int i = 0; i < 4; ++i)
      #pragma unroll
      for (int j = 0; j < 4; ++j)
        acc[i][j] = fmaf(av[i], wv[j], acc[i][j]);
  }
  // softplus + stage transposed: T[e_local][m_local]
  #pragma unroll
  for (int i = 0; i < 4; ++i)
    #pragma unroll
    for (int j = 0; j < 4; ++j)
      T[tx*4 + j][ty*4 + i] = softplus_f(acc[i][j] + dtb[e0 + tx*4 + j]);
  __syncthreads();
  // write out [e][m]: thread -> (row r=tid>>1 of 128, half h=tid&1 of 32m)
  {
    int r = tid >> 1, h = (tid & 1) * 16;
    float* dst = out + (size_t)(e0 + r)*MROWS + m0 + h;
    #pragma unroll
    for (int q = 0; q < 4; ++q) {
      float4 v = make_float4(T[r][h+q*4+0], T[r][h+q*4+1], T[r][h+q*4+2], T[r][h+q*4+3]);
      *(float4*)(dst + q*4) = v;
    }
  }
}

// ---------------------------------------------------------------------------
// Chunked two-pass selective scan, [e][m] operands (round-10 structure:
// 1536 blocks x 1024 thr, 1 state/lane). Pass-2 reduction via DPP row-shift
// adds (VALU-only) instead of ds_bpermute shfl chain; result in lane n==15.
// ---------------------------------------------------------------------------
#define SC_C 16
#define SC_P 64
__global__ __launch_bounds__(1024)
void scan_kernel(const float* __restrict__ dltf, const float* __restrict__ dltb,
                 const float* __restrict__ dbcf, const float* __restrict__ dbcb,
                 const float* __restrict__ xst,
                 const float* __restrict__ Alogf, const float* __restrict__ Alogb,
                 float* __restrict__ yf, float* __restrict__ yb) {
  __shared__ float sA[SC_C][4][16];
  __shared__ float sH[SC_C][4][16];
  __shared__ float sI[SC_C][4][16];
  const int blk = blockIdx.x;
  const int dir = blk / 768;
  const int b   = (blk % 768) / 384;
  const int e0  = (blk % 384) * 4;
  const int tid = threadIdx.x;
  const int c   = tid >> 6;
  const int lane = tid & 63;
  const int es  = lane >> 4;
  const int n   = lane & 15;
  const int e   = e0 + es;

  const float* dlt  = dir ? dltb  : dltf;
  const float* dbc  = dir ? dbcb  : dbcf;
  const float* Alog = dir ? Alogb : Alogf;
  float* y          = dir ? yb    : yf;

  // a2 = a * log2(e): dA = exp2(dl * a2)
  const float a2 = -__expf(Alog[e*D_STATE + n]) * 1.4426950408889634f;

  const int sg = dir ? -1 : 1;
  const int l0 = dir ? (LL - 1 - c*SC_P) : (c*SC_P);

  const float* dp0 = dlt + (size_t)e * MROWS + b * LL + l0;   // walk +/-1
  const float* xp0 = xst + (size_t)e * MROWS + b * LL + l0;
  const float* bp0 = dbc + ((size_t)b * LL + l0) * NDBC + DT_RANK + n;  // walk +/-80

  // ---- pass 1: chunk-local (prod dA, h_loc)
  {
    const float* d = dp0;
    const float* x = xp0;
    const float* bc = bp0;
    float Ap = 1.0f, hh = 0.0f;
    #pragma unroll 8
    for (int i = 0; i < SC_P; ++i) {
      const float dl = *d;
      const float xv = *x;
      const float Bv = *bc;
      const float dA = exp2f(dl * a2);
      hh = fmaf(dA, hh, dl * xv * Bv);
      Ap *= dA;
      d += sg; x += sg; bc += sg * NDBC;
    }
    sA[c][es][n] = Ap;
    sH[c][es][n] = hh;
  }
  __syncthreads();

  // ---- combine: exclusive prefix over chunks (wave 0 only)
  if (tid < 64) {
    float carry = 0.0f;
    #pragma unroll
    for (int cc = 0; cc < SC_C; ++cc) {
      sI[cc][es][n] = carry;
      carry = fmaf(sA[cc][es][n], carry, sH[cc][es][n]);
    }
  }
  __syncthreads();

  // ---- pass 2: re-scan from corrected initial state, emit y
  {
    const float* d = dp0;
    const float* x = xp0;
    const float* bc = bp0;
    float* yw = y + (size_t)b * LL * D_INNER + e + (size_t)l0 * D_INNER;  // walk +/-1536
    const int ystep = sg * (int)D_INNER;
    float h = sI[c][es][n];
    #pragma unroll 8
    for (int i = 0; i < SC_P; ++i) {
      const float dl = *d;
      const float xv = *x;
      const float Bv = *bc;
      const float Cv = bc[D_STATE];
      const float dA = exp2f(dl * a2);
      h = fmaf(dA, h, dl * xv * Bv);
      float p = h * Cv;
      // 16-lane row sum via DPP (result in lane 15 of each 16-lane row)
      p = dpp_shr_add<0x111>(p);   // row_shr:1
      p = dpp_shr_add<0x112>(p);   // row_shr:2
      p = dpp_shr_add<0x114>(p);   // row_shr:4
      p = dpp_shr_add<0x118>(p);   // row_shr:8
      if (n == 15) *yw = p;
      d += sg; x += sg; bc += sg * NDBC; yw += ystep;
    }
  }
}

// ---------------------------------------------------------------------------
// gate: g = (y_f + y_b + (D + D_b) * xs_c) * silu(z), emitted as hi/lo bf16
// ---------------------------------------------------------------------------
__global__ __launch_bounds__(256)
void gate_kernel(const float* __restrict__ yf, const float* __restrict__ yb,
                 const float* __restrict__ xsc, const float* __restrict__ xz,
                 const float* __restrict__ Dp, const float* __restrict__ Db,
                 ushort* __restrict__ ghi, ushort* __restrict__ glo) {
  int i4 = blockIdx.x * 256 + threadIdx.x;
  if (i4 >= MROWS * D_INNER / 4) return;
  int idx = i4 * 4;
  int e   = idx % D_INNER;
  int row = idx / D_INNER;
  float4 vf = *(const float4*)&yf[idx];
  float4 vb = *(const float4*)&yb[idx];
  float4 vx = *(const float4*)&xsc[idx];
  float4 vz = *(const float4*)&xz[(size_t)row*NXZ + D_INNER + e];
  float4 vD  = *(const float4*)&Dp[e];
  float4 vDb = *(const float4*)&Db[e];
  float4 o;
  o.x = fmaf(vD.x + vDb.x, vx.x, vf.x + vb.x) * silu_f(vz.x);
  o.y = fmaf(vD.y + vDb.y, vx.y, vf.y + vb.y) * silu_f(vz.y);
  o.z = fmaf(vD.z + vDb.z, vx.z, vf.z + vb.z) * silu_f(vz.z);
  o.w = fmaf(vD.w + vDb.w, vx.w, vf.w + vb.w) * silu_f(vz.w);
  ushort4 h, l;
  h.x = f2bf(o.x); l.x = f2bf(o.x - bf2f(h.x));
  h.y = f2bf(o.y); l.y = f2bf(o.y - bf2f(h.y));
  h.z = f2bf(o.z); l.z = f2bf(o.z - bf2f(h.z));
  h.w = f2bf(o.w); l.w = f2bf(o.w - bf2f(h.w));
  *(ushort4*)&ghi[idx] = h;
  *(ushort4*)&glo[idx] = l;
}

// ---------------------------------------------------------------------------
extern "C" void kernel_launch(void* const* d_in, const int* in_sizes, int n_in,
                              void* d_out, int out_size, void* d_ws, size_t ws_size,
                              hipStream_t stream) {
  const float* x     = (const float*)d_in[0];
  const float* ipw   = (const float*)d_in[1];
  const float* cw    = (const float*)d_in[2];
  const float* cb    = (const float*)d_in[3];
  const float* xpwf  = (const float*)d_in[4];
  const float* dtwf  = (const float*)d_in[5];
  const float* dtbf  = (const float*)d_in[6];
  const float* Alogf = (const float*)d_in[7];
  const float* Dpf   = (const float*)d_in[8];
  const float* opw   = (const float*)d_in[9];
  const float* Alogb = (const float*)d_in[10];
  const float* xpwb  = (const float*)d_in[11];
  const float* dtwb  = (const float*)d_in[12];
  const float* dtbb  = (const float*)d_in[13];
  const float* Dpb   = (const float*)d_in[14];
  float* out = (float*)d_out;

  float* ws = (float*)d_ws;
  float* xz   = ws;                                   // 2048*3072 f32
  float* xsc  = xz   + (size_t)MROWS * NXZ;           // 2048*1536 f32 [m][e]
  float* dbcf = xsc  + (size_t)MROWS * D_INNER;
  float* dbcb = dbcf + (size_t)MROWS * NDBC;
  float* dltf = dbcb + (size_t)MROWS * NDBC;          // [e][m]; reused: g hi/lo
  float* dltb = dltf + (size_t)MROWS * D_INNER;       // [e][m]
  float* yfb  = dltb + (size_t)MROWS * D_INNER;
  float* ybb  = yfb  + (size_t)MROWS * D_INNER;
  // bf16 aliases: x hi/lo in yfb region (dead until scan); ipw hi/lo in ybb.
  ushort* xhi   = (ushort*)yfb;
  ushort* xlo   = xhi   + (size_t)MROWS * D_MODEL;
  ushort* ipwhi = (ushort*)ybb;
  ushort* ipwlo = ipwhi + (size_t)NXZ * D_MODEL;
  // persistent regions after the f32 buffers:
  ushort* opwhi = (ushort*)(ybb + (size_t)MROWS * D_INNER);
  ushort* opwlo = opwhi + (size_t)D_MODEL * D_INNER;
  float*  xst   = (float*)(opwlo + (size_t)D_MODEL * D_INNER);  // xsc_t [e][m] 12.6MB
  // g hi/lo reuse the (dead-after-scan) dltf region
  ushort* ghi = (ushort*)dltf;
  ushort* glo = ghi + (size_t)MROWS * D_INNER;

  // 0) split-convert x, in_proj_w, out_proj_w to hi/lo bf16
  cvt_split_kernel<<<dim3(MROWS*D_MODEL/4/256), 256, 0, stream>>>(x, xhi, xlo, MROWS*D_MODEL/4);
  cvt_split_kernel<<<dim3(NXZ*D_MODEL/4/256), 256, 0, stream>>>(ipw, ipwhi, ipwlo, NXZ*D_MODEL/4);
  cvt_split_kernel<<<dim3(D_MODEL*D_INNER/4/256), 256, 0, stream>>>(opw, opwhi, opwlo, D_MODEL*D_INNER/4);

  // 1) xz = x @ in_proj_w^T  via MFMA (2048 x 3072, K=768)
  gemm_mfma<128,128><<<dim3(MROWS/128, NXZ/128), 256, 0, stream>>>(
      xhi, xlo, ipwhi, ipwlo, xz, MROWS, NXZ, D_MODEL);
  // 2) conv + bias + silu -> xsc [m][e]
  conv_silu_kernel<<<dim3((MROWS*D_INNER)/256), 256, 0, stream>>>(xz, cw, cb, xsc);
  // 2b) transpose xsc -> xst [e][m] for the scan
  transpose_kernel<<<dim3(MROWS/64, D_INNER/64), 256, 0, stream>>>(xsc, xst);
  // 3) zero dbc, then split-K x_proj (both dirs)
  zero_kernel<<<dim3((MROWS*2*NDBC + 255)/256), 256, 0, stream>>>(dbcf, MROWS*2*NDBC);
  xproj_kernel<<<dim3(MROWS/XP_BM, D_INNER/XP_KC), 256, 0, stream>>>(
      xsc, xpwf, xpwb, dbcf, dbcb);
  // 4) delta (both dirs) -> TRANSPOSED [e][m]
  delta_kernel<<<dim3(MROWS/32, D_INNER/128, 2), 256, 0, stream>>>(
      dbcf, dbcb, dtwf, dtwb, dtbf, dtbb, dltf, dltb);
  // 5) chunked two-pass scan (round-10 structure + DPP reduction)
  scan_kernel<<<dim3(1536), 1024, 0, stream>>>(
      dltf, dltb, dbcf, dbcb, xst, Alogf, Alogb, yfb, ybb);
  // 6) gate -> g hi/lo bf16 (dltf region dead after scan)
  gate_kernel<<<dim3((MROWS*D_INNER/4)/256), 256, 0, stream>>>(
      yfb, ybb, xsc, xz, Dpf, Dpb, ghi, glo);
  // 7) out = g @ out_proj_w^T via MFMA (2048 x 768, K=1536), 384 blocks
  gemm_mfma<64,64><<<dim3(MROWS/64, D_MODEL/64), 256, 0, stream>>>(
      ghi, glo, opwhi, opwlo, out, MROWS, D_MODEL, D_INNER);
}